// Round 15
// baseline (179.836 us; speedup 1.0000x reference)
//
#include <hip/hip_runtime.h>
#include <hip/hip_bf16.h>

// ---------------------------------------------------------------------------
// Fused MHA forward, MI355X (gfx950).
// cvt(x) -> bf16 ; merged LDS-tiled transposed cvt of W* ;
// fused GEMM {q=(x@WQ)*0.125*log2e, k=x@WK, vT=(x@WV)^T} (BM=128,BN=128,
//   NOW double-buffered 2-phase staging + XCD-chunked block remap) ;
// flash attention (R13: swapped-operand S^T=K Q^T, O^T=V^T P^T, lane-local
// exp2 softmax, zero cross-lane common path, paired q-tiles, all-valid mask
// fast-path) ; out = concat @ WO (fp32).
// Sizes: H=16, DM=1024, DK=DV=64, N=4, L=2048, M=N*L=8192.
// LESSONS: R5/R6 raw-asm permlane = wrong semantics. R7/R12 shared-K A/B
// interleave = VGPR spill at the 128-total cap (VGPR 64 + AGPR 64). R10
// unpairing = -48us. R11 8-wave = corrupt. R13 mask fast-path = -10.5us.
// R14: GEMM was 1-phase (barrier drained staging BEFORE compute) — convert
// to the attn-proven 2-phase dbuf; add T1 bijective XCD chunking (A-panel
// 2MB/XCD L2-resident).
// ---------------------------------------------------------------------------

typedef unsigned short ushort_t;
typedef __bf16 bf16x8 __attribute__((ext_vector_type(8)));
typedef float  f32x4  __attribute__((ext_vector_type(4)));
typedef unsigned short us4 __attribute__((ext_vector_type(4)));
typedef short s16x4 __attribute__((ext_vector_type(4)));

__device__ __forceinline__ ushort_t f2bf(float f) {
    union { float f; unsigned u; } a; a.f = f;
    unsigned r = a.u + 0x7fffu + ((a.u >> 16) & 1u);   // RNE
    return (ushort_t)(r >> 16);
}

__device__ __forceinline__ void gload16(const ushort_t* g, ushort_t* l) {
    __builtin_amdgcn_global_load_lds(
        (const __attribute__((address_space(1))) void*)g,
        (__attribute__((address_space(3))) void*)l, 16, 0, 0);
}

// --------------------------- converters ------------------------------------
__global__ __launch_bounds__(256) void cvt_f32_bf16(const float* __restrict__ in,
                                                    ushort_t* __restrict__ out, int n4) {
    int i = blockIdx.x * 256 + threadIdx.x;
    if (i >= n4) return;
    float4 v = reinterpret_cast<const float4*>(in)[i];
    us4 o;
    o[0] = f2bf(v.x); o[1] = f2bf(v.y); o[2] = f2bf(v.z); o[3] = f2bf(v.w);
    reinterpret_cast<us4*>(out)[i] = o;
}

// out[b][c][r] = in[b][r][c], 32x32 LDS tile, both sides coalesced.
__global__ __launch_bounds__(256) void cvt_transpose32(const float* __restrict__ in,
                                                       ushort_t* __restrict__ out,
                                                       int R, int C) {
    const int b = blockIdx.z;
    const int c0 = blockIdx.x * 32, r0 = blockIdx.y * 32;
    const int tx = threadIdx.x & 31, ty = threadIdx.x >> 5;   // 8 rows/pass
    __shared__ ushort_t t[32][33];
    const float* ip = in + ((size_t)b * R + r0) * C + c0;
    #pragma unroll
    for (int i = 0; i < 4; ++i)
        t[ty + 8 * i][tx] = f2bf(ip[(size_t)(ty + 8 * i) * C + tx]);
    __syncthreads();
    ushort_t* op = out + ((size_t)b * C + c0) * R + r0;
    #pragma unroll
    for (int i = 0; i < 4; ++i)
        op[(size_t)(ty + 8 * i) * R + tx] = t[tx][ty + 8 * i];
}

// merged WQ/WK/WV transpose: z in [0,48), slab z%16 of {WQ,WK,WV}[z/16]
__global__ __launch_bounds__(256) void cvt_transpose_qkv(const float* __restrict__ WQ,
                                                         const float* __restrict__ WK,
                                                         const float* __restrict__ WV,
                                                         ushort_t* __restrict__ out) {
    const int z = blockIdx.z;
    const float* in = (z < 16) ? WQ : (z < 32) ? WK : WV;
    const int b = z & 15;                                    // slab within input
    const int c0 = blockIdx.x * 32, r0 = blockIdx.y * 32;    // R=1024, C=64
    const int tx = threadIdx.x & 31, ty = threadIdx.x >> 5;
    __shared__ ushort_t t[32][33];
    const float* ip = in + ((size_t)b * 1024 + r0) * 64 + c0;
    #pragma unroll
    for (int i = 0; i < 4; ++i)
        t[ty + 8 * i][tx] = f2bf(ip[(size_t)(ty + 8 * i) * 64 + tx]);
    __syncthreads();
    ushort_t* op = out + (size_t)z * 65536 + (size_t)c0 * 1024 + r0;
    #pragma unroll
    for (int i = 0; i < 4; ++i)
        op[(size_t)(ty + 8 * i) * 1024 + tx] = t[tx][ty + 8 * i];
}

// --------------------------- GEMM (A[M][1024] @ BT[N'][1024]^T) -------------
// BM=128, BN=128, BK=64, 256 threads / 4 waves (2x2), 4x4 frags per wave.
// 2-PHASE: double-buffered LDS, stage(t+1) issued before compute(t), ONE
// barrier per K-step (attn-proven pattern). XCD-chunked block remap:
// nid = (lin%8)*(nwg/8) + lin/8; bm = nid/NBY (8 bm per XCD chunk -> 2MB A).
// MODE 3: fused QKV. Per-fragment slab s = 2*by + (col>>6):
//         s<16 -> q (bf16, scaled); s<32 -> k (bf16); s>=32 -> vT store.
// MODE 2: fp32 out at Cout[m*1024 + by*128 + col]             (final)
template<int MODE>
__global__ __launch_bounds__(256, 2)
void gemm_bt(const ushort_t* __restrict__ Ag, const ushort_t* __restrict__ BT,
             void* __restrict__ Cout, float scale) {
    // bijective XCD chunking (requires nwg % 8 == 0; 1536 and 512 both ok)
    const int nwg = gridDim.x * gridDim.y;
    const int lin = blockIdx.y * gridDim.x + blockIdx.x;
    const int nid = (lin & 7) * (nwg >> 3) + (lin >> 3);
    const int NBY = gridDim.y;
    const int bm = nid / NBY, by = nid - bm * NBY;

    const int tid = threadIdx.x;
    const int w = tid >> 6, lane = tid & 63;
    const int wr = w >> 1, wc = w & 1;
    const int g = lane >> 4, c = lane & 15;
    const int m0 = bm * 128;
    const ushort_t* Bbase = BT + (size_t)by * 131072;   // 128*1024

    __shared__ __align__(16) ushort_t As[2][128 * 64];  // 2 x 16 KB, swizzled
    __shared__ __align__(16) ushort_t Bs[2][128 * 64];  // 2 x 16 KB

    f32x4 acc[4][4];
    #pragma unroll
    for (int i = 0; i < 4; ++i)
        #pragma unroll
        for (int j = 0; j < 4; ++j) acc[i][j] = (f32x4){0.f, 0.f, 0.f, 0.f};

    const int rsub = (w << 3) + (lane >> 3);   // 0..31
    const int s8   = lane & 7;

    auto stage = [&](int t, int b) {
        const int k0 = t * 64;
        #pragma unroll
        for (int is = 0; is < 4; ++is) {
            const int row = is * 32 + rsub;
            const int sg  = (s8 ^ (row & 7)) << 3;
            gload16(Ag + (size_t)(m0 + row) * 1024 + k0 + sg,
                    &As[b][is * 2048 + w * 512]);
            gload16(Bbase + (size_t)row * 1024 + k0 + sg,
                    &Bs[b][is * 2048 + w * 512]);
        }
    };

    stage(0, 0);
    __syncthreads();
    int buf = 0;

    for (int t = 0; t < 16; ++t) {
        if (t < 15) stage(t + 1, buf ^ 1);     // prefetch overlaps compute
        #pragma unroll
        for (int kk = 0; kk < 2; ++kk) {
            bf16x8 af[4], bfr[4];
            #pragma unroll
            for (int mf = 0; mf < 4; ++mf) {
                const int row = wr * 64 + mf * 16 + c;
                const int slot = (kk * 4 + g) ^ (row & 7);
                af[mf] = *reinterpret_cast<const bf16x8*>(&As[buf][row * 64 + slot * 8]);
            }
            #pragma unroll
            for (int nf = 0; nf < 4; ++nf) {
                const int row = wc * 64 + nf * 16 + c;
                const int slot = (kk * 4 + g) ^ (row & 7);
                bfr[nf] = *reinterpret_cast<const bf16x8*>(&Bs[buf][row * 64 + slot * 8]);
            }
            __builtin_amdgcn_s_setprio(1);
            #pragma unroll
            for (int mf = 0; mf < 4; ++mf)
                #pragma unroll
                for (int nf = 0; nf < 4; ++nf)
                    acc[mf][nf] = __builtin_amdgcn_mfma_f32_16x16x32_bf16(
                        af[mf], bfr[nf], acc[mf][nf], 0, 0, 0);
            __builtin_amdgcn_s_setprio(0);
        }
        __syncthreads();                       // drains prefetch + guards reuse
        buf ^= 1;
    }

    #pragma unroll
    for (int mf = 0; mf < 4; ++mf) {
        const int mbase = m0 + wr * 64 + mf * 16 + g * 4;
        #pragma unroll
        for (int nf = 0; nf < 4; ++nf) {
            const int colG = wc * 64 + nf * 16 + c;
            if (MODE == 3) {
                const int s  = by * 2 + (colG >> 6);
                const int c2 = colG & 63;
                ushort_t* o = (ushort_t*)Cout + (size_t)s * 524288;
                if (s < 32) {
                    const float scl = (s < 16) ? scale : 1.0f;
                    #pragma unroll
                    for (int r = 0; r < 4; ++r)
                        o[(size_t)(mbase + r) * 64 + c2] = f2bf(acc[mf][nf][r] * scl);
                } else {
                    us4 pk;
                    #pragma unroll
                    for (int r = 0; r < 4; ++r) pk[r] = f2bf(acc[mf][nf][r]);
                    const int nIdx = mbase >> 11, l = mbase & 2047;
                    *reinterpret_cast<us4*>(
                        &o[(size_t)nIdx * 131072 + (size_t)c2 * 2048 + l]) = pk;
                }
            } else {
                float* o = (float*)Cout;
                #pragma unroll
                for (int r = 0; r < 4; ++r)
                    o[(size_t)(mbase + r) * 1024 + by * 128 + colG] = acc[mf][nf][r];
            }
        }
    }
}

// --------------------------- flash attention (R13, unchanged) ---------------
// grid (16, N, H), 256 thr / 4 waves. Block bx handles paired q-tiles
// {bx, 31-bx} (33 kv-iterations each -> balanced causal work).
// qrow = q0 + (lane&15) is lane-local; softmax in exp2 domain (q pre-scaled
// by 0.125*log2e); defer-max THR=8 gated on LANE-LOCAL max; lrun lane-partial
// (reduced at epilogue); P packed via v_cvt_pk_bf16_f32; block-level
// all-valid mask fast-path (prologue scan).
__global__ __launch_bounds__(256, 4)
void attn_kernel(const ushort_t* __restrict__ qb, const ushort_t* __restrict__ kb,
                 const ushort_t* __restrict__ vtb, const float* __restrict__ mi,
                 ushort_t* __restrict__ cat) {
    const int bx = blockIdx.x;                    // 0..15
    const int n = blockIdx.y, h = blockIdx.z;
    const int tid = threadIdx.x;
    const int w = tid >> 6, lane = tid & 63;
    const int g = lane >> 4, c = lane & 15;
    const int qblkA = bx, qblkB = 31 - bx;        // (bx+1)+(32-bx) = 33 iters
    const int q0A = qblkA * 64 + w * 16;
    const int q0B = qblkB * 64 + w * 16;

    const ushort_t* qhn = qb  + (size_t)h * 524288 + (size_t)n * 131072;  // [2048][64]
    const ushort_t* khn = kb  + (size_t)h * 524288 + (size_t)n * 131072;  // [2048][64]
    const ushort_t* vhn = vtb + (size_t)h * 524288 + (size_t)n * 131072;  // [64][2048]
    const float*    mrow = mi + (size_t)n * 2048;

    __shared__ __align__(16) ushort_t Ks[2][64 * 64];  // 16 KB (swizzled)
    __shared__ __align__(16) ushort_t Vs[2][64 * 64];  // 16 KB
    __shared__ int s_allv;

    const int rsub = (w << 3) + (lane >> 3);   // 0..31
    const int s8   = lane & 7;

    auto stage = [&](int jb, int b) {
        const int kbase = jb * 64;
        #pragma unroll
        for (int is = 0; is < 2; ++is) {
            const int row = is * 32 + rsub;
            const int sg  = (s8 ^ (row & 7)) << 3;
            gload16(khn + (size_t)(kbase + row) * 64 + sg, &Ks[b][is * 2048 + w * 512]);
            gload16(vhn + (size_t)row * 2048 + kbase + sg, &Vs[b][is * 2048 + w * 512]);
        }
    };

    // ---- prologue: scan masked_info once; all-valid => skip bias per pass --
    if (tid == 0) s_allv = 1;
    stage(0, 0);
    {
        const int kmax4 = (qblkB + 1) * 16;       // (qblkB+1)*64 floats / 4
        bool ok = true;
        for (int i = tid; i < kmax4; i += 256) {
            float4 v = reinterpret_cast<const float4*>(mrow)[i];
            ok &= (v.x != 0.f) & (v.y != 0.f) & (v.z != 0.f) & (v.w != 0.f);
        }
        __syncthreads();                          // covers stage(0) + s_allv init
        if (!__all(ok)) s_allv = 0;               // benign race: only 0 written
        __syncthreads();
    }
    const bool allv = (s_allv != 0);

    // Q B-frags: qf[kk] = Q[q0 + c][kk*32 + g*8 .. +7]
    bf16x8 qfA[2], qfB[2];
    {
        const ushort_t* qa = qhn + (size_t)(q0A + c) * 64 + g * 8;
        const ushort_t* qb2 = qhn + (size_t)(q0B + c) * 64 + g * 8;
        qfA[0] = *reinterpret_cast<const bf16x8*>(qa);
        qfA[1] = *reinterpret_cast<const bf16x8*>(qa + 32);
        qfB[0] = *reinterpret_cast<const bf16x8*>(qb2);
        qfB[1] = *reinterpret_cast<const bf16x8*>(qb2 + 32);
    }
    const float mqA = mrow[q0A + c];
    const float mqB = mrow[q0B + c];

    // mrun: q-row-uniform; lrun: LANE-PARTIAL (reduced at epilogue)
    float mrunA = -1e30f, lrunA = 0.f, mrunB = -1e30f, lrunB = 0.f;
    f32x4 accA[4], accB[4];
    #pragma unroll
    for (int i = 0; i < 4; ++i) {
        accA[i] = (f32x4){0.f, 0.f, 0.f, 0.f};
        accB[i] = (f32x4){0.f, 0.f, 0.f, 0.f};
    }

    int buf = 0;

    for (int j = 0; j <= qblkB; ++j) {
        if (j < qblkB) stage(j + 1, buf ^ 1);
        const int kbase = j * 64;
        // per-tile additive pad-mask bias — built ONLY when padding exists
        f32x4 bias[4];
        if (!allv) {
            #pragma unroll
            for (int nf = 0; nf < 4; ++nf) {
                float4 mk = *reinterpret_cast<const float4*>(&mrow[kbase + nf * 16 + g * 4]);
                bias[nf][0] = (mk.x == 0.f) ? -1e30f : 0.f;
                bias[nf][1] = (mk.y == 0.f) ? -1e30f : 0.f;
                bias[nf][2] = (mk.z == 0.f) ? -1e30f : 0.f;
                bias[nf][3] = (mk.w == 0.f) ? -1e30f : 0.f;
            }
        }

        auto do_pass = [&](const bf16x8* qf, f32x4* acc, float& mrun, float& lrun,
                           int q0, bool diag) {
            // ---- S^T = K @ Q^T : 8 x mfma 16x16x32 (exp2 domain) ----
            f32x4 s[4];
            #pragma unroll
            for (int nf = 0; nf < 4; ++nf) s[nf] = (f32x4){0.f, 0.f, 0.f, 0.f};
            __builtin_amdgcn_s_setprio(1);
            #pragma unroll
            for (int kk = 0; kk < 2; ++kk)
                #pragma unroll
                for (int nf = 0; nf < 4; ++nf) {
                    const int row  = nf * 16 + c;
                    const int byte = row * 128 + (((kk * 4 + g) ^ (c & 7)) << 4);
                    bf16x8 kf = *reinterpret_cast<const bf16x8*>(
                        reinterpret_cast<const char*>(&Ks[buf][0]) + byte);
                    s[nf] = __builtin_amdgcn_mfma_f32_16x16x32_bf16(
                        kf, qf[kk], s[nf], 0, 0, 0);
                }
            __builtin_amdgcn_s_setprio(0);
            // ---- mask: pad bias (only if padding present) + causal ----
            if (!allv) {
                #pragma unroll
                for (int nf = 0; nf < 4; ++nf) s[nf] += bias[nf];
            }
            if (diag) {
                const int qrow = q0 + c;
                #pragma unroll
                for (int nf = 0; nf < 4; ++nf)
                    #pragma unroll
                    for (int r = 0; r < 4; ++r)
                        if (kbase + nf * 16 + g * 4 + r > qrow) s[nf][r] = -1e30f;
            }
            // ---- lane-local max; cross-lane reduce ONLY on threshold breach --
            float m01[4], m23[4];
            #pragma unroll
            for (int r = 0; r < 4; ++r) {
                m01[r] = fmaxf(s[0][r], s[1][r]);
                m23[r] = fmaxf(s[2][r], s[3][r]);
            }
            const float mtl = fmaxf(fmaxf(fmaxf(m01[0], m01[1]), fmaxf(m01[2], m01[3])),
                                    fmaxf(fmaxf(m23[0], m23[1]), fmaxf(m23[2], m23[3])));
            if (!__all(mtl - mrun <= 8.0f)) {
                float mt = fmaxf(mtl, __shfl_xor(mtl, 16));
                mt = fmaxf(mt, __shfl_xor(mt, 32));
                const float mnew = fmaxf(mrun, mt);
                const float sc = __builtin_amdgcn_exp2f(mrun - mnew);
                #pragma unroll
                for (int nfd = 0; nfd < 4; ++nfd)
                    #pragma unroll
                    for (int r = 0; r < 4; ++r) acc[nfd][r] *= sc;
                lrun *= sc;                       // lane-partial, sc row-uniform
                mrun = mnew;
            }
            // ---- exp2 + bf16 pack; sum stays lane-partial (no shuffles) ----
            float rs = 0.f;
            union { unsigned u[2]; s16x4 v; } pb[4];
            #pragma unroll
            for (int nf = 0; nf < 4; ++nf) {
                const float p0 = __builtin_amdgcn_exp2f(s[nf][0] - mrun);
                const float p1 = __builtin_amdgcn_exp2f(s[nf][1] - mrun);
                const float p2 = __builtin_amdgcn_exp2f(s[nf][2] - mrun);
                const float p3 = __builtin_amdgcn_exp2f(s[nf][3] - mrun);
                rs += (p0 + p1) + (p2 + p3);
                asm("v_cvt_pk_bf16_f32 %0, %1, %2" : "=v"(pb[nf].u[0]) : "v"(p0), "v"(p1));
                asm("v_cvt_pk_bf16_f32 %0, %1, %2" : "=v"(pb[nf].u[1]) : "v"(p2), "v"(p3));
            }
            lrun += rs;
            // ---- O^T += V^T @ P^T : 16 x mfma 16x16x16 (P in registers) ----
            __builtin_amdgcn_s_setprio(1);
            #pragma unroll
            for (int kk = 0; kk < 4; ++kk)
                #pragma unroll
                for (int nfd = 0; nfd < 4; ++nfd) {
                    const int row   = nfd * 16 + c;
                    const int chunk = (kk * 2 + (g >> 1)) ^ (c & 7);
                    const int byt   = row * 128 + (chunk << 4) + (g & 1) * 8;
                    s16x4 vf = *reinterpret_cast<const s16x4*>(
                        reinterpret_cast<const char*>(&Vs[buf][0]) + byt);
                    acc[nfd] = __builtin_amdgcn_mfma_f32_16x16x16bf16_1k(
                        vf, pb[kk].v, acc[nfd], 0, 0, 0);
                }
            __builtin_amdgcn_s_setprio(0);
        };

        if (j <= qblkA) do_pass(qfA, accA, mrunA, lrunA, q0A, j == qblkA);
        do_pass(qfB, accB, mrunB, lrunB, q0B, j == qblkB);

        __syncthreads();
        buf ^= 1;
    }

    // ---- epilogue: reduce lane-partial lrun, O^T/l -> concat (bf16) ----
    auto epi = [&](const f32x4* acc, float mrun, float lrun, float mq, int q0) {
        float lt = lrun;
        lt += __shfl_xor(lt, 16);
        lt += __shfl_xor(lt, 32);
        const float inv = (mq != 0.f && mrun > -1e29f && lt > 0.f)
                              ? (1.0f / lt) : 0.f;
        const size_t base = (size_t)(n * 2048 + q0 + c) * 1024 + h * 64;
        #pragma unroll
        for (int nfd = 0; nfd < 4; ++nfd) {
            us4 pk;
            #pragma unroll
            for (int r = 0; r < 4; ++r) pk[r] = f2bf(acc[nfd][r] * inv);
            *reinterpret_cast<us4*>(&cat[base + nfd * 16 + g * 4]) = pk;
        }
    };
    epi(accA, mrunA, lrunA, mqA, q0A);
    epi(accB, mrunB, lrunB, mqB, q0B);
}

// --------------------------- launcher ---------------------------------------
extern "C" void kernel_launch(void* const* d_in, const int* in_sizes, int n_in,
                              void* d_out, int out_size, void* d_ws, size_t ws_size,
                              hipStream_t stream) {
    const float* x  = (const float*)d_in[0];
    const float* mi = (const float*)d_in[1];
    const float* WQ = (const float*)d_in[2];
    const float* WK = (const float*)d_in[3];
    const float* WV = (const float*)d_in[4];
    const float* WO = (const float*)d_in[5];
    float* out = (float*)d_out;

    ushort_t* ws  = (ushort_t*)d_ws;
    ushort_t* xb  = ws;                    // 8192*1024           = 8388608
    ushort_t* wqt = xb  + 8388608;         // 48 slabs of 64*1024 (wq/wk/wv)
    ushort_t* wot = wqt + 3145728;         // 1024*1024           = 1048576
    ushort_t* qb  = wot + 1048576;         // [16][4][2048][64]   = 8388608
    ushort_t* kb  = qb  + 8388608;         // (qb/kb/vtb contiguous)
    ushort_t* vtb = kb  + 8388608;         // [16][4][64][2048]
    ushort_t* cat = xb;                    // reuse xb after QKV GEMM (16 MB)

    cvt_f32_bf16<<<8192, 256, 0, stream>>>(x, xb, 2097152);
    {
        dim3 gt(2, 32, 48);                // C/32, R/32, 48 slabs
        cvt_transpose_qkv<<<gt, 256, 0, stream>>>(WQ, WK, WV, wqt);
        dim3 go(32, 32, 1);
        cvt_transpose32<<<go, 256, 0, stream>>>(WO, wot, 1024, 1024);
    }

    // fused QKV: slabs 0-15 q (scaled 0.125*log2e), 16-31 k, 32-47 vT
    dim3 g1(64, 24);                       // nwg = 1536 (%8==0 for XCD remap)
    gemm_bt<3><<<g1, 256, 0, stream>>>(xb, wqt, qb, 0.18033688f);

    dim3 g2(16, 4, 16);
    attn_kernel<<<g2, 256, 0, stream>>>(qb, kb, vtb, mi, cat);

    dim3 g3(64, 8);                        // nwg = 512 (%8==0)
    gemm_bt<2><<<g3, 256, 0, stream>>>(cat, wot, out, 1.0f);   // out fp32
}

// Round 16
// 174.373 us; speedup vs baseline: 1.0313x; 1.0313x over previous
//
#include <hip/hip_runtime.h>
#include <hip/hip_bf16.h>

// ---------------------------------------------------------------------------
// Fused MHA forward, MI355X (gfx950).  [R13 configuration — session best]
// cvt(x) -> bf16 ; merged LDS-tiled transposed cvt of W* ;
// fused GEMM {q=(x@WQ)*0.125*log2e, k=x@WK, vT=(x@WV)^T} (BM=128,BN=128) ;
// flash attention (swapped-operand S^T=K Q^T, O^T=V^T P^T, lane-local exp2
// softmax, zero cross-lane ops on common path, paired q-tiles {bx,31-bx},
// serial A/B passes, block-level all-valid mask fast-path) ;
// out = concat @ WO (fp32).
// Sizes: H=16, DM=1024, DK=DV=64, N=4, L=2048, M=N*L=8192.
// LESSONS: R5/R6 raw-asm permlane = wrong semantics. R7/R12 shared-K A/B
// interleave = VGPR spill at the 128-total cap (VGPR 64 + AGPR 64). R10
// unpairing = -48us (pairing ILP load-bearing). R11 8-wave = corrupt.
// R13 mask fast-path = -10.5us. R14 GEMM dbuf(64KB LDS: 5->2 blocks/CU) +
// XCD chunk (B-set 6MB > 4MB L2) = +5us REGRESSION — reverted; 1-phase
// GEMM at 32KB LDS is the local optimum.
// ---------------------------------------------------------------------------

typedef unsigned short ushort_t;
typedef __bf16 bf16x8 __attribute__((ext_vector_type(8)));
typedef float  f32x4  __attribute__((ext_vector_type(4)));
typedef unsigned short us4 __attribute__((ext_vector_type(4)));
typedef short s16x4 __attribute__((ext_vector_type(4)));

__device__ __forceinline__ ushort_t f2bf(float f) {
    union { float f; unsigned u; } a; a.f = f;
    unsigned r = a.u + 0x7fffu + ((a.u >> 16) & 1u);   // RNE
    return (ushort_t)(r >> 16);
}

__device__ __forceinline__ void gload16(const ushort_t* g, ushort_t* l) {
    __builtin_amdgcn_global_load_lds(
        (const __attribute__((address_space(1))) void*)g,
        (__attribute__((address_space(3))) void*)l, 16, 0, 0);
}

// --------------------------- converters ------------------------------------
__global__ __launch_bounds__(256) void cvt_f32_bf16(const float* __restrict__ in,
                                                    ushort_t* __restrict__ out, int n4) {
    int i = blockIdx.x * 256 + threadIdx.x;
    if (i >= n4) return;
    float4 v = reinterpret_cast<const float4*>(in)[i];
    us4 o;
    o[0] = f2bf(v.x); o[1] = f2bf(v.y); o[2] = f2bf(v.z); o[3] = f2bf(v.w);
    reinterpret_cast<us4*>(out)[i] = o;
}

// out[b][c][r] = in[b][r][c], 32x32 LDS tile, both sides coalesced.
__global__ __launch_bounds__(256) void cvt_transpose32(const float* __restrict__ in,
                                                       ushort_t* __restrict__ out,
                                                       int R, int C) {
    const int b = blockIdx.z;
    const int c0 = blockIdx.x * 32, r0 = blockIdx.y * 32;
    const int tx = threadIdx.x & 31, ty = threadIdx.x >> 5;   // 8 rows/pass
    __shared__ ushort_t t[32][33];
    const float* ip = in + ((size_t)b * R + r0) * C + c0;
    #pragma unroll
    for (int i = 0; i < 4; ++i)
        t[ty + 8 * i][tx] = f2bf(ip[(size_t)(ty + 8 * i) * C + tx]);
    __syncthreads();
    ushort_t* op = out + ((size_t)b * C + c0) * R + r0;
    #pragma unroll
    for (int i = 0; i < 4; ++i)
        op[(size_t)(ty + 8 * i) * R + tx] = t[tx][ty + 8 * i];
}

// merged WQ/WK/WV transpose: z in [0,48), slab z%16 of {WQ,WK,WV}[z/16]
__global__ __launch_bounds__(256) void cvt_transpose_qkv(const float* __restrict__ WQ,
                                                         const float* __restrict__ WK,
                                                         const float* __restrict__ WV,
                                                         ushort_t* __restrict__ out) {
    const int z = blockIdx.z;
    const float* in = (z < 16) ? WQ : (z < 32) ? WK : WV;
    const int b = z & 15;                                    // slab within input
    const int c0 = blockIdx.x * 32, r0 = blockIdx.y * 32;    // R=1024, C=64
    const int tx = threadIdx.x & 31, ty = threadIdx.x >> 5;
    __shared__ ushort_t t[32][33];
    const float* ip = in + ((size_t)b * 1024 + r0) * 64 + c0;
    #pragma unroll
    for (int i = 0; i < 4; ++i)
        t[ty + 8 * i][tx] = f2bf(ip[(size_t)(ty + 8 * i) * 64 + tx]);
    __syncthreads();
    ushort_t* op = out + (size_t)z * 65536 + (size_t)c0 * 1024 + r0;
    #pragma unroll
    for (int i = 0; i < 4; ++i)
        op[(size_t)(ty + 8 * i) * 1024 + tx] = t[tx][ty + 8 * i];
}

// --------------------------- GEMM (A[M][1024] @ BT[N'][1024]^T) -------------
// BM=128, BN=128, BK=64, 256 threads / 4 waves (2x2), 4x4 frags per wave.
// 1-phase staging (32KB LDS -> 5 blocks/CU; R14 proved dbuf/remap regress).
// MODE 3: fused QKV. Per-fragment slab s = 2*by + (col>>6):
//         s<16 -> q (bf16, scaled); s<32 -> k (bf16); s>=32 -> vT store.
// MODE 2: fp32 out at Cout[m*1024 + by*128 + col]             (final)
template<int MODE>
__global__ __launch_bounds__(256, 2)
void gemm_bt(const ushort_t* __restrict__ Ag, const ushort_t* __restrict__ BT,
             void* __restrict__ Cout, float scale) {
    const int bm = blockIdx.x, by = blockIdx.y;
    const int tid = threadIdx.x;
    const int w = tid >> 6, lane = tid & 63;
    const int wr = w >> 1, wc = w & 1;
    const int g = lane >> 4, c = lane & 15;
    const int m0 = bm * 128;
    const ushort_t* Bbase = BT + (size_t)by * 131072;   // 128*1024

    __shared__ __align__(16) ushort_t As[128 * 64];    // 16 KB, swizzled
    __shared__ __align__(16) ushort_t Bs[128 * 64];    // 16 KB, swizzled

    f32x4 acc[4][4];
    #pragma unroll
    for (int i = 0; i < 4; ++i)
        #pragma unroll
        for (int j = 0; j < 4; ++j) acc[i][j] = (f32x4){0.f, 0.f, 0.f, 0.f};

    const int rsub = (w << 3) + (lane >> 3);   // 0..31
    const int s8   = lane & 7;

    for (int t = 0; t < 16; ++t) {
        const int k0 = t * 64;
        #pragma unroll
        for (int is = 0; is < 4; ++is) {
            const int row = is * 32 + rsub;
            const int sg  = (s8 ^ (row & 7)) << 3;
            gload16(Ag + (size_t)(m0 + row) * 1024 + k0 + sg, &As[is * 2048 + w * 512]);
            gload16(Bbase + (size_t)row * 1024 + k0 + sg,     &Bs[is * 2048 + w * 512]);
        }
        __syncthreads();
        #pragma unroll
        for (int kk = 0; kk < 2; ++kk) {
            bf16x8 af[4], bfr[4];
            #pragma unroll
            for (int mf = 0; mf < 4; ++mf) {
                const int row = wr * 64 + mf * 16 + c;
                const int slot = (kk * 4 + g) ^ (row & 7);
                af[mf] = *reinterpret_cast<const bf16x8*>(&As[row * 64 + slot * 8]);
            }
            #pragma unroll
            for (int nf = 0; nf < 4; ++nf) {
                const int row = wc * 64 + nf * 16 + c;
                const int slot = (kk * 4 + g) ^ (row & 7);
                bfr[nf] = *reinterpret_cast<const bf16x8*>(&Bs[row * 64 + slot * 8]);
            }
            __builtin_amdgcn_s_setprio(1);
            #pragma unroll
            for (int mf = 0; mf < 4; ++mf)
                #pragma unroll
                for (int nf = 0; nf < 4; ++nf)
                    acc[mf][nf] = __builtin_amdgcn_mfma_f32_16x16x32_bf16(
                        af[mf], bfr[nf], acc[mf][nf], 0, 0, 0);
            __builtin_amdgcn_s_setprio(0);
        }
        __syncthreads();
    }

    #pragma unroll
    for (int mf = 0; mf < 4; ++mf) {
        const int mbase = m0 + wr * 64 + mf * 16 + g * 4;
        #pragma unroll
        for (int nf = 0; nf < 4; ++nf) {
            const int colG = wc * 64 + nf * 16 + c;
            if (MODE == 3) {
                const int s  = by * 2 + (colG >> 6);
                const int c2 = colG & 63;
                ushort_t* o = (ushort_t*)Cout + (size_t)s * 524288;
                if (s < 32) {
                    const float scl = (s < 16) ? scale : 1.0f;
                    #pragma unroll
                    for (int r = 0; r < 4; ++r)
                        o[(size_t)(mbase + r) * 64 + c2] = f2bf(acc[mf][nf][r] * scl);
                } else {
                    us4 pk;
                    #pragma unroll
                    for (int r = 0; r < 4; ++r) pk[r] = f2bf(acc[mf][nf][r]);
                    const int nIdx = mbase >> 11, l = mbase & 2047;
                    *reinterpret_cast<us4*>(
                        &o[(size_t)nIdx * 131072 + (size_t)c2 * 2048 + l]) = pk;
                }
            } else {
                float* o = (float*)Cout;
                #pragma unroll
                for (int r = 0; r < 4; ++r)
                    o[(size_t)(mbase + r) * 1024 + by * 128 + colG] = acc[mf][nf][r];
            }
        }
    }
}

// --------------------------- flash attention --------------------------------
// grid (16, N, H), 256 thr / 4 waves. Block bx handles paired q-tiles
// {bx, 31-bx} (33 kv-iterations each -> balanced causal work).
// qrow = q0 + (lane&15) is lane-local; softmax in exp2 domain (q pre-scaled
// by 0.125*log2e); defer-max THR=8 gated on LANE-LOCAL max; lrun lane-partial
// (reduced at epilogue); P packed via v_cvt_pk_bf16_f32.
// Block-level all-valid mask fast-path (prologue scan): if all tokens in
// [0, kmax) are valid, per-pass pad-bias work is skipped entirely.
__global__ __launch_bounds__(256, 4)
void attn_kernel(const ushort_t* __restrict__ qb, const ushort_t* __restrict__ kb,
                 const ushort_t* __restrict__ vtb, const float* __restrict__ mi,
                 ushort_t* __restrict__ cat) {
    const int bx = blockIdx.x;                    // 0..15
    const int n = blockIdx.y, h = blockIdx.z;
    const int tid = threadIdx.x;
    const int w = tid >> 6, lane = tid & 63;
    const int g = lane >> 4, c = lane & 15;
    const int qblkA = bx, qblkB = 31 - bx;        // (bx+1)+(32-bx) = 33 iters
    const int q0A = qblkA * 64 + w * 16;
    const int q0B = qblkB * 64 + w * 16;

    const ushort_t* qhn = qb  + (size_t)h * 524288 + (size_t)n * 131072;  // [2048][64]
    const ushort_t* khn = kb  + (size_t)h * 524288 + (size_t)n * 131072;  // [2048][64]
    const ushort_t* vhn = vtb + (size_t)h * 524288 + (size_t)n * 131072;  // [64][2048]
    const float*    mrow = mi + (size_t)n * 2048;

    __shared__ __align__(16) ushort_t Ks[2][64 * 64];  // 16 KB (swizzled)
    __shared__ __align__(16) ushort_t Vs[2][64 * 64];  // 16 KB
    __shared__ int s_allv;

    const int rsub = (w << 3) + (lane >> 3);   // 0..31
    const int s8   = lane & 7;

    auto stage = [&](int jb, int b) {
        const int kbase = jb * 64;
        #pragma unroll
        for (int is = 0; is < 2; ++is) {
            const int row = is * 32 + rsub;
            const int sg  = (s8 ^ (row & 7)) << 3;
            gload16(khn + (size_t)(kbase + row) * 64 + sg, &Ks[b][is * 2048 + w * 512]);
            gload16(vhn + (size_t)row * 2048 + kbase + sg, &Vs[b][is * 2048 + w * 512]);
        }
    };

    // ---- prologue: scan masked_info once; all-valid => skip bias per pass --
    if (tid == 0) s_allv = 1;
    stage(0, 0);
    {
        const int kmax4 = (qblkB + 1) * 16;       // (qblkB+1)*64 floats / 4
        bool ok = true;
        for (int i = tid; i < kmax4; i += 256) {
            float4 v = reinterpret_cast<const float4*>(mrow)[i];
            ok &= (v.x != 0.f) & (v.y != 0.f) & (v.z != 0.f) & (v.w != 0.f);
        }
        __syncthreads();                          // covers stage(0) + s_allv init
        if (!__all(ok)) s_allv = 0;               // benign race: only 0 written
        __syncthreads();
    }
    const bool allv = (s_allv != 0);

    // Q B-frags: qf[kk] = Q[q0 + c][kk*32 + g*8 .. +7]
    bf16x8 qfA[2], qfB[2];
    {
        const ushort_t* qa = qhn + (size_t)(q0A + c) * 64 + g * 8;
        const ushort_t* qb2 = qhn + (size_t)(q0B + c) * 64 + g * 8;
        qfA[0] = *reinterpret_cast<const bf16x8*>(qa);
        qfA[1] = *reinterpret_cast<const bf16x8*>(qa + 32);
        qfB[0] = *reinterpret_cast<const bf16x8*>(qb2);
        qfB[1] = *reinterpret_cast<const bf16x8*>(qb2 + 32);
    }
    const float mqA = mrow[q0A + c];
    const float mqB = mrow[q0B + c];

    // mrun: q-row-uniform; lrun: LANE-PARTIAL (reduced at epilogue)
    float mrunA = -1e30f, lrunA = 0.f, mrunB = -1e30f, lrunB = 0.f;
    f32x4 accA[4], accB[4];
    #pragma unroll
    for (int i = 0; i < 4; ++i) {
        accA[i] = (f32x4){0.f, 0.f, 0.f, 0.f};
        accB[i] = (f32x4){0.f, 0.f, 0.f, 0.f};
    }

    int buf = 0;

    for (int j = 0; j <= qblkB; ++j) {
        if (j < qblkB) stage(j + 1, buf ^ 1);
        const int kbase = j * 64;
        // per-tile additive pad-mask bias — built ONLY when padding exists
        f32x4 bias[4];
        if (!allv) {
            #pragma unroll
            for (int nf = 0; nf < 4; ++nf) {
                float4 mk = *reinterpret_cast<const float4*>(&mrow[kbase + nf * 16 + g * 4]);
                bias[nf][0] = (mk.x == 0.f) ? -1e30f : 0.f;
                bias[nf][1] = (mk.y == 0.f) ? -1e30f : 0.f;
                bias[nf][2] = (mk.z == 0.f) ? -1e30f : 0.f;
                bias[nf][3] = (mk.w == 0.f) ? -1e30f : 0.f;
            }
        }

        auto do_pass = [&](const bf16x8* qf, f32x4* acc, float& mrun, float& lrun,
                           int q0, bool diag) {
            // ---- S^T = K @ Q^T : 8 x mfma 16x16x32 (exp2 domain) ----
            f32x4 s[4];
            #pragma unroll
            for (int nf = 0; nf < 4; ++nf) s[nf] = (f32x4){0.f, 0.f, 0.f, 0.f};
            __builtin_amdgcn_s_setprio(1);
            #pragma unroll
            for (int kk = 0; kk < 2; ++kk)
                #pragma unroll
                for (int nf = 0; nf < 4; ++nf) {
                    const int row  = nf * 16 + c;
                    const int byte = row * 128 + (((kk * 4 + g) ^ (c & 7)) << 4);
                    bf16x8 kf = *reinterpret_cast<const bf16x8*>(
                        reinterpret_cast<const char*>(&Ks[buf][0]) + byte);
                    s[nf] = __builtin_amdgcn_mfma_f32_16x16x32_bf16(
                        kf, qf[kk], s[nf], 0, 0, 0);
                }
            __builtin_amdgcn_s_setprio(0);
            // ---- mask: pad bias (only if padding present) + causal ----
            if (!allv) {
                #pragma unroll
                for (int nf = 0; nf < 4; ++nf) s[nf] += bias[nf];
            }
            if (diag) {
                const int qrow = q0 + c;
                #pragma unroll
                for (int nf = 0; nf < 4; ++nf)
                    #pragma unroll
                    for (int r = 0; r < 4; ++r)
                        if (kbase + nf * 16 + g * 4 + r > qrow) s[nf][r] = -1e30f;
            }
            // ---- lane-local max; cross-lane reduce ONLY on threshold breach --
            float m01[4], m23[4];
            #pragma unroll
            for (int r = 0; r < 4; ++r) {
                m01[r] = fmaxf(s[0][r], s[1][r]);
                m23[r] = fmaxf(s[2][r], s[3][r]);
            }
            const float mtl = fmaxf(fmaxf(fmaxf(m01[0], m01[1]), fmaxf(m01[2], m01[3])),
                                    fmaxf(fmaxf(m23[0], m23[1]), fmaxf(m23[2], m23[3])));
            if (!__all(mtl - mrun <= 8.0f)) {
                float mt = fmaxf(mtl, __shfl_xor(mtl, 16));
                mt = fmaxf(mt, __shfl_xor(mt, 32));
                const float mnew = fmaxf(mrun, mt);
                const float sc = __builtin_amdgcn_exp2f(mrun - mnew);
                #pragma unroll
                for (int nfd = 0; nfd < 4; ++nfd)
                    #pragma unroll
                    for (int r = 0; r < 4; ++r) acc[nfd][r] *= sc;
                lrun *= sc;                       // lane-partial, sc row-uniform
                mrun = mnew;
            }
            // ---- exp2 + bf16 pack; sum stays lane-partial (no shuffles) ----
            float rs = 0.f;
            union { unsigned u[2]; s16x4 v; } pb[4];
            #pragma unroll
            for (int nf = 0; nf < 4; ++nf) {
                const float p0 = __builtin_amdgcn_exp2f(s[nf][0] - mrun);
                const float p1 = __builtin_amdgcn_exp2f(s[nf][1] - mrun);
                const float p2 = __builtin_amdgcn_exp2f(s[nf][2] - mrun);
                const float p3 = __builtin_amdgcn_exp2f(s[nf][3] - mrun);
                rs += (p0 + p1) + (p2 + p3);
                asm("v_cvt_pk_bf16_f32 %0, %1, %2" : "=v"(pb[nf].u[0]) : "v"(p0), "v"(p1));
                asm("v_cvt_pk_bf16_f32 %0, %1, %2" : "=v"(pb[nf].u[1]) : "v"(p2), "v"(p3));
            }
            lrun += rs;
            // ---- O^T += V^T @ P^T : 16 x mfma 16x16x16 (P in registers) ----
            __builtin_amdgcn_s_setprio(1);
            #pragma unroll
            for (int kk = 0; kk < 4; ++kk)
                #pragma unroll
                for (int nfd = 0; nfd < 4; ++nfd) {
                    const int row   = nfd * 16 + c;
                    const int chunk = (kk * 2 + (g >> 1)) ^ (c & 7);
                    const int byt   = row * 128 + (chunk << 4) + (g & 1) * 8;
                    s16x4 vf = *reinterpret_cast<const s16x4*>(
                        reinterpret_cast<const char*>(&Vs[buf][0]) + byt);
                    acc[nfd] = __builtin_amdgcn_mfma_f32_16x16x16bf16_1k(
                        vf, pb[kk].v, acc[nfd], 0, 0, 0);
                }
            __builtin_amdgcn_s_setprio(0);
        };

        if (j <= qblkA) do_pass(qfA, accA, mrunA, lrunA, q0A, j == qblkA);
        do_pass(qfB, accB, mrunB, lrunB, q0B, j == qblkB);

        __syncthreads();
        buf ^= 1;
    }

    // ---- epilogue: reduce lane-partial lrun, O^T/l -> concat (bf16) ----
    auto epi = [&](const f32x4* acc, float mrun, float lrun, float mq, int q0) {
        float lt = lrun;
        lt += __shfl_xor(lt, 16);
        lt += __shfl_xor(lt, 32);
        const float inv = (mq != 0.f && mrun > -1e29f && lt > 0.f)
                              ? (1.0f / lt) : 0.f;
        const size_t base = (size_t)(n * 2048 + q0 + c) * 1024 + h * 64;
        #pragma unroll
        for (int nfd = 0; nfd < 4; ++nfd) {
            us4 pk;
            #pragma unroll
            for (int r = 0; r < 4; ++r) pk[r] = f2bf(acc[nfd][r] * inv);
            *reinterpret_cast<us4*>(&cat[base + nfd * 16 + g * 4]) = pk;
        }
    };
    epi(accA, mrunA, lrunA, mqA, q0A);
    epi(accB, mrunB, lrunB, mqB, q0B);
}

// --------------------------- launcher ---------------------------------------
extern "C" void kernel_launch(void* const* d_in, const int* in_sizes, int n_in,
                              void* d_out, int out_size, void* d_ws, size_t ws_size,
                              hipStream_t stream) {
    const float* x  = (const float*)d_in[0];
    const float* mi = (const float*)d_in[1];
    const float* WQ = (const float*)d_in[2];
    const float* WK = (const float*)d_in[3];
    const float* WV = (const float*)d_in[4];
    const float* WO = (const float*)d_in[5];
    float* out = (float*)d_out;

    ushort_t* ws  = (ushort_t*)d_ws;
    ushort_t* xb  = ws;                    // 8192*1024           = 8388608
    ushort_t* wqt = xb  + 8388608;         // 48 slabs of 64*1024 (wq/wk/wv)
    ushort_t* wot = wqt + 3145728;         // 1024*1024           = 1048576
    ushort_t* qb  = wot + 1048576;         // [16][4][2048][64]   = 8388608
    ushort_t* kb  = qb  + 8388608;         // (qb/kb/vtb contiguous)
    ushort_t* vtb = kb  + 8388608;         // [16][4][64][2048]
    ushort_t* cat = xb;                    // reuse xb after QKV GEMM (16 MB)

    cvt_f32_bf16<<<8192, 256, 0, stream>>>(x, xb, 2097152);
    {
        dim3 gt(2, 32, 48);                // C/32, R/32, 48 slabs
        cvt_transpose_qkv<<<gt, 256, 0, stream>>>(WQ, WK, WV, wqt);
        dim3 go(32, 32, 1);
        cvt_transpose32<<<go, 256, 0, stream>>>(WO, wot, 1024, 1024);
    }

    // fused QKV: slabs 0-15 q (scaled 0.125*log2e), 16-31 k, 32-47 vT
    dim3 g1(64, 24);
    gemm_bt<3><<<g1, 256, 0, stream>>>(xb, wqt, qb, 0.18033688f);

    dim3 g2(16, 4, 16);
    attn_kernel<<<g2, 256, 0, stream>>>(qb, kb, vtb, mi, cat);

    dim3 g3(64, 8);
    gemm_bt<2><<<g3, 256, 0, stream>>>(cat, wot, out, 1.0f);   // out fp32
}

// Round 17
// 173.148 us; speedup vs baseline: 1.0386x; 1.0071x over previous
//
#include <hip/hip_runtime.h>
#include <hip/hip_bf16.h>

// ---------------------------------------------------------------------------
// Fused MHA forward, MI355X (gfx950).  [R13 base + R16 attn CU-balance remap]
// cvt(x) -> bf16 ; merged LDS-tiled transposed cvt of W* ;
// fused GEMM {q=(x@WQ)*0.125*log2e, k=x@WK, vT=(x@WV)^T} (BM=128,BN=128) ;
// flash attention (swapped-operand S^T=K Q^T, O^T=V^T P^T, lane-local exp2
// softmax, zero cross-lane ops on common path, paired q-tiles {bx,31-bx},
// serial A/B passes, all-valid mask fast-path, + iteration-balancing bx
// permutation so each CU's 4 resident blocks sum to 98 iterations) ;
// out = concat @ WO (fp32).
// Sizes: H=16, DM=1024, DK=DV=64, N=4, L=2048, M=N*L=8192.
// LESSONS: R5/R6 raw-asm permlane = wrong semantics. R7/R12 shared-K A/B
// interleave = VGPR spill at the 128-total cap (VGPR 64 + AGPR 64). R10
// unpairing = -48us. R11 8-wave = corrupt. R13 mask fast-path = -10.5us.
// R14 GEMM dbuf/XCD-chunk = +5us regression (reverted). R16: attn runs as
// ONE generation (1024 blocks = 1024 slots); dispatch gives each CU 4 blocks
// of the SAME bx -> CU totals 68..128 iters, wall = 128 (occupancy 34% is
// imbalance, not resources). Remap bx by u=(h>>2)&3 so each CU gets
// {b,15-b,c,15-c} = 98 iters exactly. Bijective => perf-only.
// ---------------------------------------------------------------------------

typedef unsigned short ushort_t;
typedef __bf16 bf16x8 __attribute__((ext_vector_type(8)));
typedef float  f32x4  __attribute__((ext_vector_type(4)));
typedef unsigned short us4 __attribute__((ext_vector_type(4)));
typedef short s16x4 __attribute__((ext_vector_type(4)));

__device__ __forceinline__ ushort_t f2bf(float f) {
    union { float f; unsigned u; } a; a.f = f;
    unsigned r = a.u + 0x7fffu + ((a.u >> 16) & 1u);   // RNE
    return (ushort_t)(r >> 16);
}

__device__ __forceinline__ void gload16(const ushort_t* g, ushort_t* l) {
    __builtin_amdgcn_global_load_lds(
        (const __attribute__((address_space(1))) void*)g,
        (__attribute__((address_space(3))) void*)l, 16, 0, 0);
}

// --------------------------- converters ------------------------------------
__global__ __launch_bounds__(256) void cvt_f32_bf16(const float* __restrict__ in,
                                                    ushort_t* __restrict__ out, int n4) {
    int i = blockIdx.x * 256 + threadIdx.x;
    if (i >= n4) return;
    float4 v = reinterpret_cast<const float4*>(in)[i];
    us4 o;
    o[0] = f2bf(v.x); o[1] = f2bf(v.y); o[2] = f2bf(v.z); o[3] = f2bf(v.w);
    reinterpret_cast<us4*>(out)[i] = o;
}

// out[b][c][r] = in[b][r][c], 32x32 LDS tile, both sides coalesced.
__global__ __launch_bounds__(256) void cvt_transpose32(const float* __restrict__ in,
                                                       ushort_t* __restrict__ out,
                                                       int R, int C) {
    const int b = blockIdx.z;
    const int c0 = blockIdx.x * 32, r0 = blockIdx.y * 32;
    const int tx = threadIdx.x & 31, ty = threadIdx.x >> 5;   // 8 rows/pass
    __shared__ ushort_t t[32][33];
    const float* ip = in + ((size_t)b * R + r0) * C + c0;
    #pragma unroll
    for (int i = 0; i < 4; ++i)
        t[ty + 8 * i][tx] = f2bf(ip[(size_t)(ty + 8 * i) * C + tx]);
    __syncthreads();
    ushort_t* op = out + ((size_t)b * C + c0) * R + r0;
    #pragma unroll
    for (int i = 0; i < 4; ++i)
        op[(size_t)(ty + 8 * i) * R + tx] = t[tx][ty + 8 * i];
}

// merged WQ/WK/WV transpose: z in [0,48), slab z%16 of {WQ,WK,WV}[z/16]
__global__ __launch_bounds__(256) void cvt_transpose_qkv(const float* __restrict__ WQ,
                                                         const float* __restrict__ WK,
                                                         const float* __restrict__ WV,
                                                         ushort_t* __restrict__ out) {
    const int z = blockIdx.z;
    const float* in = (z < 16) ? WQ : (z < 32) ? WK : WV;
    const int b = z & 15;                                    // slab within input
    const int c0 = blockIdx.x * 32, r0 = blockIdx.y * 32;    // R=1024, C=64
    const int tx = threadIdx.x & 31, ty = threadIdx.x >> 5;
    __shared__ ushort_t t[32][33];
    const float* ip = in + ((size_t)b * 1024 + r0) * 64 + c0;
    #pragma unroll
    for (int i = 0; i < 4; ++i)
        t[ty + 8 * i][tx] = f2bf(ip[(size_t)(ty + 8 * i) * 64 + tx]);
    __syncthreads();
    ushort_t* op = out + (size_t)z * 65536 + (size_t)c0 * 1024 + r0;
    #pragma unroll
    for (int i = 0; i < 4; ++i)
        op[(size_t)(ty + 8 * i) * 1024 + tx] = t[tx][ty + 8 * i];
}

// --------------------------- GEMM (A[M][1024] @ BT[N'][1024]^T) -------------
// BM=128, BN=128, BK=64, 256 threads / 4 waves (2x2), 4x4 frags per wave.
// 1-phase staging (32KB LDS; R14 proved dbuf/remap regress).
// MODE 3: fused QKV. Per-fragment slab s = 2*by + (col>>6):
//         s<16 -> q (bf16, scaled); s<32 -> k (bf16); s>=32 -> vT store.
// MODE 2: fp32 out at Cout[m*1024 + by*128 + col]             (final)
template<int MODE>
__global__ __launch_bounds__(256, 2)
void gemm_bt(const ushort_t* __restrict__ Ag, const ushort_t* __restrict__ BT,
             void* __restrict__ Cout, float scale) {
    const int bm = blockIdx.x, by = blockIdx.y;
    const int tid = threadIdx.x;
    const int w = tid >> 6, lane = tid & 63;
    const int wr = w >> 1, wc = w & 1;
    const int g = lane >> 4, c = lane & 15;
    const int m0 = bm * 128;
    const ushort_t* Bbase = BT + (size_t)by * 131072;   // 128*1024

    __shared__ __align__(16) ushort_t As[128 * 64];    // 16 KB, swizzled
    __shared__ __align__(16) ushort_t Bs[128 * 64];    // 16 KB, swizzled

    f32x4 acc[4][4];
    #pragma unroll
    for (int i = 0; i < 4; ++i)
        #pragma unroll
        for (int j = 0; j < 4; ++j) acc[i][j] = (f32x4){0.f, 0.f, 0.f, 0.f};

    const int rsub = (w << 3) + (lane >> 3);   // 0..31
    const int s8   = lane & 7;

    for (int t = 0; t < 16; ++t) {
        const int k0 = t * 64;
        #pragma unroll
        for (int is = 0; is < 4; ++is) {
            const int row = is * 32 + rsub;
            const int sg  = (s8 ^ (row & 7)) << 3;
            gload16(Ag + (size_t)(m0 + row) * 1024 + k0 + sg, &As[is * 2048 + w * 512]);
            gload16(Bbase + (size_t)row * 1024 + k0 + sg,     &Bs[is * 2048 + w * 512]);
        }
        __syncthreads();
        #pragma unroll
        for (int kk = 0; kk < 2; ++kk) {
            bf16x8 af[4], bfr[4];
            #pragma unroll
            for (int mf = 0; mf < 4; ++mf) {
                const int row = wr * 64 + mf * 16 + c;
                const int slot = (kk * 4 + g) ^ (row & 7);
                af[mf] = *reinterpret_cast<const bf16x8*>(&As[row * 64 + slot * 8]);
            }
            #pragma unroll
            for (int nf = 0; nf < 4; ++nf) {
                const int row = wc * 64 + nf * 16 + c;
                const int slot = (kk * 4 + g) ^ (row & 7);
                bfr[nf] = *reinterpret_cast<const bf16x8*>(&Bs[row * 64 + slot * 8]);
            }
            __builtin_amdgcn_s_setprio(1);
            #pragma unroll
            for (int mf = 0; mf < 4; ++mf)
                #pragma unroll
                for (int nf = 0; nf < 4; ++nf)
                    acc[mf][nf] = __builtin_amdgcn_mfma_f32_16x16x32_bf16(
                        af[mf], bfr[nf], acc[mf][nf], 0, 0, 0);
            __builtin_amdgcn_s_setprio(0);
        }
        __syncthreads();
    }

    #pragma unroll
    for (int mf = 0; mf < 4; ++mf) {
        const int mbase = m0 + wr * 64 + mf * 16 + g * 4;
        #pragma unroll
        for (int nf = 0; nf < 4; ++nf) {
            const int colG = wc * 64 + nf * 16 + c;
            if (MODE == 3) {
                const int s  = by * 2 + (colG >> 6);
                const int c2 = colG & 63;
                ushort_t* o = (ushort_t*)Cout + (size_t)s * 524288;
                if (s < 32) {
                    const float scl = (s < 16) ? scale : 1.0f;
                    #pragma unroll
                    for (int r = 0; r < 4; ++r)
                        o[(size_t)(mbase + r) * 64 + c2] = f2bf(acc[mf][nf][r] * scl);
                } else {
                    us4 pk;
                    #pragma unroll
                    for (int r = 0; r < 4; ++r) pk[r] = f2bf(acc[mf][nf][r]);
                    const int nIdx = mbase >> 11, l = mbase & 2047;
                    *reinterpret_cast<us4*>(
                        &o[(size_t)nIdx * 131072 + (size_t)c2 * 2048 + l]) = pk;
                }
            } else {
                float* o = (float*)Cout;
                #pragma unroll
                for (int r = 0; r < 4; ++r)
                    o[(size_t)(mbase + r) * 1024 + by * 128 + colG] = acc[mf][nf][r];
            }
        }
    }
}

// --------------------------- flash attention --------------------------------
// grid (16, N, H), 256 thr / 4 waves. Block handles paired q-tiles
// {bx, 31-bx} (33 pass-executions; 32-bx loop iterations).
// R16: bx is a u-dependent permutation of blockIdx.x (u=(h>>2)&3) so the 4
// blocks co-resident on a CU (ids 256 apart => same x, h+={0,4,8,12}) have
// iteration counts {32-b, 17+b, 31-c', 18+c'} summing to 98 for every x.
// qrow = q0 + (lane&15) lane-local; exp2-domain softmax (q pre-scaled
// 0.125*log2e); defer-max THR=8 on lane-local max; lrun lane-partial;
// P packed via v_cvt_pk_bf16_f32; all-valid mask fast-path.
__global__ __launch_bounds__(256, 4)
void attn_kernel(const ushort_t* __restrict__ qb, const ushort_t* __restrict__ kb,
                 const ushort_t* __restrict__ vtb, const float* __restrict__ mi,
                 ushort_t* __restrict__ cat) {
    const int n = blockIdx.y, h = blockIdx.z;
    // iteration-balancing bijective remap (perf-only; correctness for any
    // dispatch since bx'(blockIdx.x) is a bijection for each fixed h)
    const int u = (h >> 2) & 3;
    int bx = blockIdx.x;
    if (u >= 2) bx = (bx + 1) & 15;
    if (u & 1)  bx = 15 - bx;
    const int tid = threadIdx.x;
    const int w = tid >> 6, lane = tid & 63;
    const int g = lane >> 4, c = lane & 15;
    const int qblkA = bx, qblkB = 31 - bx;        // (bx+1)+(32-bx) = 33 passes
    const int q0A = qblkA * 64 + w * 16;
    const int q0B = qblkB * 64 + w * 16;

    const ushort_t* qhn = qb  + (size_t)h * 524288 + (size_t)n * 131072;  // [2048][64]
    const ushort_t* khn = kb  + (size_t)h * 524288 + (size_t)n * 131072;  // [2048][64]
    const ushort_t* vhn = vtb + (size_t)h * 524288 + (size_t)n * 131072;  // [64][2048]
    const float*    mrow = mi + (size_t)n * 2048;

    __shared__ __align__(16) ushort_t Ks[2][64 * 64];  // 16 KB (swizzled)
    __shared__ __align__(16) ushort_t Vs[2][64 * 64];  // 16 KB
    __shared__ int s_allv;

    const int rsub = (w << 3) + (lane >> 3);   // 0..31
    const int s8   = lane & 7;

    auto stage = [&](int jb, int b) {
        const int kbase = jb * 64;
        #pragma unroll
        for (int is = 0; is < 2; ++is) {
            const int row = is * 32 + rsub;
            const int sg  = (s8 ^ (row & 7)) << 3;
            gload16(khn + (size_t)(kbase + row) * 64 + sg, &Ks[b][is * 2048 + w * 512]);
            gload16(vhn + (size_t)row * 2048 + kbase + sg, &Vs[b][is * 2048 + w * 512]);
        }
    };

    // ---- prologue: scan masked_info once; all-valid => skip bias per pass --
    if (tid == 0) s_allv = 1;
    stage(0, 0);
    {
        const int kmax4 = (qblkB + 1) * 16;       // (qblkB+1)*64 floats / 4
        bool ok = true;
        for (int i = tid; i < kmax4; i += 256) {
            float4 v = reinterpret_cast<const float4*>(mrow)[i];
            ok &= (v.x != 0.f) & (v.y != 0.f) & (v.z != 0.f) & (v.w != 0.f);
        }
        __syncthreads();                          // covers stage(0) + s_allv init
        if (!__all(ok)) s_allv = 0;               // benign race: only 0 written
        __syncthreads();
    }
    const bool allv = (s_allv != 0);

    // Q B-frags: qf[kk] = Q[q0 + c][kk*32 + g*8 .. +7]
    bf16x8 qfA[2], qfB[2];
    {
        const ushort_t* qa = qhn + (size_t)(q0A + c) * 64 + g * 8;
        const ushort_t* qb2 = qhn + (size_t)(q0B + c) * 64 + g * 8;
        qfA[0] = *reinterpret_cast<const bf16x8*>(qa);
        qfA[1] = *reinterpret_cast<const bf16x8*>(qa + 32);
        qfB[0] = *reinterpret_cast<const bf16x8*>(qb2);
        qfB[1] = *reinterpret_cast<const bf16x8*>(qb2 + 32);
    }
    const float mqA = mrow[q0A + c];
    const float mqB = mrow[q0B + c];

    // mrun: q-row-uniform; lrun: LANE-PARTIAL (reduced at epilogue)
    float mrunA = -1e30f, lrunA = 0.f, mrunB = -1e30f, lrunB = 0.f;
    f32x4 accA[4], accB[4];
    #pragma unroll
    for (int i = 0; i < 4; ++i) {
        accA[i] = (f32x4){0.f, 0.f, 0.f, 0.f};
        accB[i] = (f32x4){0.f, 0.f, 0.f, 0.f};
    }

    int buf = 0;

    for (int j = 0; j <= qblkB; ++j) {
        if (j < qblkB) stage(j + 1, buf ^ 1);
        const int kbase = j * 64;
        // per-tile additive pad-mask bias — built ONLY when padding exists
        f32x4 bias[4];
        if (!allv) {
            #pragma unroll
            for (int nf = 0; nf < 4; ++nf) {
                float4 mk = *reinterpret_cast<const float4*>(&mrow[kbase + nf * 16 + g * 4]);
                bias[nf][0] = (mk.x == 0.f) ? -1e30f : 0.f;
                bias[nf][1] = (mk.y == 0.f) ? -1e30f : 0.f;
                bias[nf][2] = (mk.z == 0.f) ? -1e30f : 0.f;
                bias[nf][3] = (mk.w == 0.f) ? -1e30f : 0.f;
            }
        }

        auto do_pass = [&](const bf16x8* qf, f32x4* acc, float& mrun, float& lrun,
                           int q0, bool diag) {
            // ---- S^T = K @ Q^T : 8 x mfma 16x16x32 (exp2 domain) ----
            f32x4 s[4];
            #pragma unroll
            for (int nf = 0; nf < 4; ++nf) s[nf] = (f32x4){0.f, 0.f, 0.f, 0.f};
            __builtin_amdgcn_s_setprio(1);
            #pragma unroll
            for (int kk = 0; kk < 2; ++kk)
                #pragma unroll
                for (int nf = 0; nf < 4; ++nf) {
                    const int row  = nf * 16 + c;
                    const int byte = row * 128 + (((kk * 4 + g) ^ (c & 7)) << 4);
                    bf16x8 kf = *reinterpret_cast<const bf16x8*>(
                        reinterpret_cast<const char*>(&Ks[buf][0]) + byte);
                    s[nf] = __builtin_amdgcn_mfma_f32_16x16x32_bf16(
                        kf, qf[kk], s[nf], 0, 0, 0);
                }
            __builtin_amdgcn_s_setprio(0);
            // ---- mask: pad bias (only if padding present) + causal ----
            if (!allv) {
                #pragma unroll
                for (int nf = 0; nf < 4; ++nf) s[nf] += bias[nf];
            }
            if (diag) {
                const int qrow = q0 + c;
                #pragma unroll
                for (int nf = 0; nf < 4; ++nf)
                    #pragma unroll
                    for (int r = 0; r < 4; ++r)
                        if (kbase + nf * 16 + g * 4 + r > qrow) s[nf][r] = -1e30f;
            }
            // ---- lane-local max; cross-lane reduce ONLY on threshold breach --
            float m01[4], m23[4];
            #pragma unroll
            for (int r = 0; r < 4; ++r) {
                m01[r] = fmaxf(s[0][r], s[1][r]);
                m23[r] = fmaxf(s[2][r], s[3][r]);
            }
            const float mtl = fmaxf(fmaxf(fmaxf(m01[0], m01[1]), fmaxf(m01[2], m01[3])),
                                    fmaxf(fmaxf(m23[0], m23[1]), fmaxf(m23[2], m23[3])));
            if (!__all(mtl - mrun <= 8.0f)) {
                float mt = fmaxf(mtl, __shfl_xor(mtl, 16));
                mt = fmaxf(mt, __shfl_xor(mt, 32));
                const float mnew = fmaxf(mrun, mt);
                const float sc = __builtin_amdgcn_exp2f(mrun - mnew);
                #pragma unroll
                for (int nfd = 0; nfd < 4; ++nfd)
                    #pragma unroll
                    for (int r = 0; r < 4; ++r) acc[nfd][r] *= sc;
                lrun *= sc;                       // lane-partial, sc row-uniform
                mrun = mnew;
            }
            // ---- exp2 + bf16 pack; sum stays lane-partial (no shuffles) ----
            float rs = 0.f;
            union { unsigned u2[2]; s16x4 v; } pb[4];
            #pragma unroll
            for (int nf = 0; nf < 4; ++nf) {
                const float p0 = __builtin_amdgcn_exp2f(s[nf][0] - mrun);
                const float p1 = __builtin_amdgcn_exp2f(s[nf][1] - mrun);
                const float p2 = __builtin_amdgcn_exp2f(s[nf][2] - mrun);
                const float p3 = __builtin_amdgcn_exp2f(s[nf][3] - mrun);
                rs += (p0 + p1) + (p2 + p3);
                asm("v_cvt_pk_bf16_f32 %0, %1, %2" : "=v"(pb[nf].u2[0]) : "v"(p0), "v"(p1));
                asm("v_cvt_pk_bf16_f32 %0, %1, %2" : "=v"(pb[nf].u2[1]) : "v"(p2), "v"(p3));
            }
            lrun += rs;
            // ---- O^T += V^T @ P^T : 16 x mfma 16x16x16 (P in registers) ----
            __builtin_amdgcn_s_setprio(1);
            #pragma unroll
            for (int kk = 0; kk < 4; ++kk)
                #pragma unroll
                for (int nfd = 0; nfd < 4; ++nfd) {
                    const int row   = nfd * 16 + c;
                    const int chunk = (kk * 2 + (g >> 1)) ^ (c & 7);
                    const int byt   = row * 128 + (chunk << 4) + (g & 1) * 8;
                    s16x4 vf = *reinterpret_cast<const s16x4*>(
                        reinterpret_cast<const char*>(&Vs[buf][0]) + byt);
                    acc[nfd] = __builtin_amdgcn_mfma_f32_16x16x16bf16_1k(
                        vf, pb[kk].v, acc[nfd], 0, 0, 0);
                }
            __builtin_amdgcn_s_setprio(0);
        };

        if (j <= qblkA) do_pass(qfA, accA, mrunA, lrunA, q0A, j == qblkA);
        do_pass(qfB, accB, mrunB, lrunB, q0B, j == qblkB);

        __syncthreads();
        buf ^= 1;
    }

    // ---- epilogue: reduce lane-partial lrun, O^T/l -> concat (bf16) ----
    auto epi = [&](const f32x4* acc, float mrun, float lrun, float mq, int q0) {
        float lt = lrun;
        lt += __shfl_xor(lt, 16);
        lt += __shfl_xor(lt, 32);
        const float inv = (mq != 0.f && mrun > -1e29f && lt > 0.f)
                              ? (1.0f / lt) : 0.f;
        const size_t base = (size_t)(n * 2048 + q0 + c) * 1024 + h * 64;
        #pragma unroll
        for (int nfd = 0; nfd < 4; ++nfd) {
            us4 pk;
            #pragma unroll
            for (int r = 0; r < 4; ++r) pk[r] = f2bf(acc[nfd][r] * inv);
            *reinterpret_cast<us4*>(&cat[base + nfd * 16 + g * 4]) = pk;
        }
    };
    epi(accA, mrunA, lrunA, mqA, q0A);
    epi(accB, mrunB, lrunB, mqB, q0B);
}

// --------------------------- launcher ---------------------------------------
extern "C" void kernel_launch(void* const* d_in, const int* in_sizes, int n_in,
                              void* d_out, int out_size, void* d_ws, size_t ws_size,
                              hipStream_t stream) {
    const float* x  = (const float*)d_in[0];
    const float* mi = (const float*)d_in[1];
    const float* WQ = (const float*)d_in[2];
    const float* WK = (const float*)d_in[3];
    const float* WV = (const float*)d_in[4];
    const float* WO = (const float*)d_in[5];
    float* out = (float*)d_out;

    ushort_t* ws  = (ushort_t*)d_ws;
    ushort_t* xb  = ws;                    // 8192*1024           = 8388608
    ushort_t* wqt = xb  + 8388608;         // 48 slabs of 64*1024 (wq/wk/wv)
    ushort_t* wot = wqt + 3145728;         // 1024*1024           = 1048576
    ushort_t* qb  = wot + 1048576;         // [16][4][2048][64]   = 8388608
    ushort_t* kb  = qb  + 8388608;         // (qb/kb/vtb contiguous)
    ushort_t* vtb = kb  + 8388608;         // [16][4][64][2048]
    ushort_t* cat = xb;                    // reuse xb after QKV GEMM (16 MB)

    cvt_f32_bf16<<<8192, 256, 0, stream>>>(x, xb, 2097152);
    {
        dim3 gt(2, 32, 48);                // C/32, R/32, 48 slabs
        cvt_transpose_qkv<<<gt, 256, 0, stream>>>(WQ, WK, WV, wqt);
        dim3 go(32, 32, 1);
        cvt_transpose32<<<go, 256, 0, stream>>>(WO, wot, 1024, 1024);
    }

    // fused QKV: slabs 0-15 q (scaled 0.125*log2e), 16-31 k, 32-47 vT
    dim3 g1(64, 24);
    gemm_bt<3><<<g1, 256, 0, stream>>>(xb, wqt, qb, 0.18033688f);

    dim3 g2(16, 4, 16);
    attn_kernel<<<g2, 256, 0, stream>>>(qb, kb, vtb, mi, cat);

    dim3 g3(64, 8);
    gemm_bt<2><<<g3, 256, 0, stream>>>(cat, wot, out, 1.0f);   // out fp32
}